// Round 7
// baseline (247.040 us; speedup 1.0000x reference)
//
#include <hip/hip_runtime.h>
#include <hip/hip_cooperative_groups.h>
#include <float.h>
#include <math.h>

namespace cg = cooperative_groups;

#define PPIL   40000
#define NPTS   32
#define COUT   64
#define PPB    16              // pillars per chunk
#define NBLK   1250            // coop blocks; each does chunks bid and bid+NBLK
#define NBLK_F 2500            // fallback main blocks (1 chunk each)
#define PSTRIDE 132            // floats per pillar slot (33 float4: bank spread)
#define NSB    32              // stats reducer blocks (coop)
#define NSB_F  16              // stats reducer blocks (fallback)

__device__ __forceinline__ float shfl_xor_f(float v, int m) {
    return __shfl_xor(v, m, 64);
}

// ===========================================================================
// Shared per-chunk worker: stage 16 pillars, pillar tree, affine phase 2.
// Accumulates s1/s2 into s1a/s2a, returns per-channel maxima in mxv[8].
// ===========================================================================
__device__ __forceinline__ void process_chunk(
    const float* __restrict__ features, const int* __restrict__ num_voxels,
    const int* __restrict__ coors, int pb, int tid,
    float* lds_f, float (*lds_pc)[12], const float* lds_w,
    const float g0[8], const float g1[8], const float g2[8], const float g3[8],
    float s1a[8], float s2a[8], float mxv[8])
{
    const int pl2 = tid >> 3;      // pillar in chunk, 0..15
    const int cg  = tid & 7;       // channel group

    // per-pillar scalars
    if (tid < PPB) {
        const int p = pb + tid;
        lds_pc[tid][3] = (float)coors[p * 4 + 3] * 0.2f + 0.1f;    // ax
        lds_pc[tid][4] = (float)coors[p * 4 + 2] * 0.2f - 39.9f;   // by
        lds_pc[tid][5] = (float)num_voxels[p];
    }

    // coalesced unmasked stage
    #pragma unroll
    for (int j = 0; j < 4; ++j) {
        const int idx = tid + 128 * j;        // 0..511
        const int pl  = idx >> 5, n = idx & 31;
        const float4 f = *(const float4*)(features + ((size_t)(pb + pl) * NPTS + n) * 4);
        *(float4*)&lds_f[pl * PSTRIDE + n * 4] = f;
    }
    __syncthreads();

    // pillar-sum tree: 8 threads per pillar, 4 points each
    {
        const int pl = tid >> 3, sub = tid & 7;
        const int nv = (int)lds_pc[pl][5];
        float sx = 0.f, sy = 0.f, sz = 0.f;
        float t0 = 0.f, t1 = 0.f, t2 = 0.f, t3 = 0.f;
        #pragma unroll
        for (int i = 0; i < 4; ++i) {
            const int n = sub + 8 * i;
            const float4 f = *(const float4*)&lds_f[pl * PSTRIDE + n * 4];
            sx += f.x; sy += f.y; sz += f.z;
            const float m = (n < nv) ? 1.0f : 0.0f;
            t0 = fmaf(f.x, m, t0); t1 = fmaf(f.y, m, t1);
            t2 = fmaf(f.z, m, t2); t3 = fmaf(f.w, m, t3);
        }
        #pragma unroll
        for (int m = 1; m <= 4; m <<= 1) {
            sx += shfl_xor_f(sx, m); sy += shfl_xor_f(sy, m); sz += shfl_xor_f(sz, m);
            t0 += shfl_xor_f(t0, m); t1 += shfl_xor_f(t1, m);
            t2 += shfl_xor_f(t2, m); t3 += shfl_xor_f(t3, m);
        }
        if (sub == 0) {
            const float inv = 1.0f / lds_pc[pl][5];
            lds_pc[pl][0] = sx * inv;
            lds_pc[pl][1] = sy * inv;
            lds_pc[pl][2] = sz * inv;
            lds_pc[pl][6] = t0; lds_pc[pl][7] = t1;
            lds_pc[pl][8] = t2; lds_pc[pl][9] = t3;
        }
    }
    __syncthreads();

    // phase 2
    const float* pc = lds_pc[pl2];
    const float mxp = pc[0], myp = pc[1], mzp = pc[2], axp = pc[3], byp = pc[4];
    const float nvf = pc[5];
    const float Fm0 = pc[6], Fm1 = pc[7], Fm2 = pc[8], Fm3 = pc[9];
    const int   nvi = (int)nvf;

    float cc[8];
    #pragma unroll
    for (int k = 0; k < 8; ++k) {
        const float* wp = &lds_w[(cg + 8 * k) * 9];
        cc[k] = -(wp[4] * mxp + wp[5] * myp + wp[6] * mzp + wp[7] * axp + wp[8] * byp);
    }

    float s2[8];
    #pragma unroll
    for (int k = 0; k < 8; ++k) { s2[k] = 0.0f; mxv[k] = -FLT_MAX; }

    const float4* fb = (const float4*)&lds_f[pl2 * PSTRIDE];
    #pragma unroll 2
    for (int n = 0; n < NPTS; ++n) {
        const float4 f = fb[n];
        const float mskf = (n < nvi) ? 1.0f : 0.0f;
        #pragma unroll
        for (int k = 0; k < 8; ++k) {
            float x = cc[k];
            x = fmaf(g0[k], f.x, x);
            x = fmaf(g1[k], f.y, x);
            x = fmaf(g2[k], f.z, x);
            x = fmaf(g3[k], f.w, x);
            x *= mskf;                        // exact 0 for masked rows
            s2[k]  = fmaf(x, x, s2[k]);
            mxv[k] = fmaxf(mxv[k], x);
        }
    }

    #pragma unroll
    for (int k = 0; k < 8; ++k) {
        float d = g0[k] * Fm0;
        d = fmaf(g1[k], Fm1, d);
        d = fmaf(g2[k], Fm2, d);
        d = fmaf(g3[k], Fm3, d);
        s1a[k] += fmaf(nvf, cc[k], d);
        s2a[k] += s2[k];
    }
}

__device__ __forceinline__ void weight_prep(const float* __restrict__ linear_w,
                                            float* lds_w, int tid)
{
    if (tid < 64) {
        const float* wr = linear_w + tid * 9;
        const float w0 = wr[0], w1 = wr[1], w2 = wr[2], w3 = wr[3], w4 = wr[4];
        const float w5 = wr[5], w6 = wr[6], w7 = wr[7], w8 = wr[8];
        float* dw = &lds_w[tid * 9];
        dw[0] = w0 + w4 + w7;
        dw[1] = w1 + w5 + w8;
        dw[2] = w2 + w6;
        dw[3] = w3;
        dw[4] = w4; dw[5] = w5; dw[6] = w6; dw[7] = w7; dw[8] = w8;
    }
}

// ===========================================================================
// Cooperative single-kernel path.
// __launch_bounds__(128, 4): cap VGPR<=128, 4 waves/EU -> 8 blocks/CU ->
// 2048 resident capacity >= 1250 (coop launch legality + latency hiding).
// ===========================================================================
__global__ __launch_bounds__(128, 4) void pfn_fused(
    const float* __restrict__ features, const int* __restrict__ num_voxels,
    const int* __restrict__ coors, const float* __restrict__ linear_w,
    const float* __restrict__ gamma, const float* __restrict__ beta,
    float* __restrict__ out, float* __restrict__ partials,
    float* __restrict__ partials2)
{
    __shared__ float  lds_f[PPB * PSTRIDE];
    __shared__ float  lds_pc[PPB][12];
    __shared__ float  lds_w[64 * 9];
    __shared__ float  lds_red[2][8][16];
    __shared__ double dred[128];
    __shared__ float  sb[128];

    const int tid = threadIdx.x;
    const int bid = blockIdx.x;
    const int pl2 = tid >> 3;
    const int cg  = tid & 7;

    weight_prep(linear_w, lds_w, tid);
    __syncthreads();

    float g0[8], g1[8], g2[8], g3[8];
    #pragma unroll
    for (int k = 0; k < 8; ++k) {
        const float* wp = &lds_w[(cg + 8 * k) * 9];
        g0[k] = wp[0]; g1[k] = wp[1]; g2[k] = wp[2]; g3[k] = wp[3];
    }

    float s1a[8], s2a[8], mxa0[8], mxa1[8];
    #pragma unroll
    for (int k = 0; k < 8; ++k) { s1a[k] = 0.f; s2a[k] = 0.f; }

    process_chunk(features, num_voxels, coors, bid * PPB, tid,
                  lds_f, lds_pc, lds_w, g0, g1, g2, g3, s1a, s2a, mxa0);
    __syncthreads();
    process_chunk(features, num_voxels, coors, (bid + NBLK) * PPB, tid,
                  lds_f, lds_pc, lds_w, g0, g1, g2, g3, s1a, s2a, mxa1);

    // block reduce s1a/s2a -> partials[bid][128]
    #pragma unroll
    for (int k = 0; k < 8; ++k) {
        #pragma unroll
        for (int m = 8; m <= 32; m <<= 1) {
            s1a[k] += shfl_xor_f(s1a[k], m);
            s2a[k] += shfl_xor_f(s2a[k], m);
        }
    }
    {
        const int lane = tid & 63, wv = tid >> 6;
        if (lane < 8) {
            #pragma unroll
            for (int k = 0; k < 8; ++k) {
                lds_red[wv][lane][k]     = s1a[k];
                lds_red[wv][lane][8 + k] = s2a[k];
            }
        }
    }
    __syncthreads();
    {
        const int cg2 = tid >> 4, v = tid & 15;
        partials[bid * 128 + tid] = lds_red[0][cg2][v] + lds_red[1][cg2][v];
    }

    cg::this_grid().sync();

    if (bid < NSB) {
        double a0 = 0.0, a1 = 0.0, a2 = 0.0, a3 = 0.0;
        int m = 0;
        for (; m + 4 <= 36; m += 4) {
            a0 += (double)partials[(bid + NSB * (m + 0)) * 128 + tid];
            a1 += (double)partials[(bid + NSB * (m + 1)) * 128 + tid];
            a2 += (double)partials[(bid + NSB * (m + 2)) * 128 + tid];
            a3 += (double)partials[(bid + NSB * (m + 3)) * 128 + tid];
        }
        for (; m < 40; ++m) {
            const int r = bid + NSB * m;
            if (r < NBLK) a0 += (double)partials[r * 128 + tid];
        }
        partials2[bid * 128 + tid] = (float)((a0 + a1) + (a2 + a3));
    }

    cg::this_grid().sync();

    {
        double s = 0.0;
        #pragma unroll
        for (int b = 0; b < NSB; ++b) s += (double)partials2[b * 128 + tid];
        dred[tid] = s;
    }
    __syncthreads();
    if (tid < 64) {
        const int cgx = tid & 7, k = tid >> 3;
        const double s1 = dred[cgx * 16 + k];
        const double s2 = dred[cgx * 16 + 8 + k];
        const double PN = (double)PPIL * (double)NPTS;
        const double mean = s1 / PN;
        const double var  = s2 / PN - mean * mean;
        const double scale = (double)gamma[tid] / sqrt(var + 1e-3);
        sb[tid]      = (float)scale;
        sb[64 + tid] = (float)((double)beta[tid] - mean * scale);
    }
    __syncthreads();

    #pragma unroll
    for (int c = 0; c < 2; ++c) {
        const int p = (bid + c * NBLK) * PPB + pl2;
        float* rp = out + (size_t)p * COUT + cg;
        #pragma unroll
        for (int k = 0; k < 8; ++k) {
            const int u = cg + 8 * k;
            const float mx = (c == 0) ? mxa0[k] : mxa1[k];
            rp[8 * k] = fmaxf(fmaf(mx, sb[u], sb[64 + u]), 0.0f);
        }
    }
}

// ===========================================================================
// Fallback 3-kernel path (R5 structure + occupancy fix on main).
// ===========================================================================
__global__ __launch_bounds__(128, 4) void pfn_main(
    const float* __restrict__ features, const int* __restrict__ num_voxels,
    const int* __restrict__ coors, const float* __restrict__ linear_w,
    float* __restrict__ rawmax, float* __restrict__ partials)
{
    __shared__ float lds_f[PPB * PSTRIDE];
    __shared__ float lds_pc[PPB][12];
    __shared__ float lds_w[64 * 9];
    __shared__ float lds_red[2][8][16];

    const int tid = threadIdx.x;
    const int bid = blockIdx.x;
    const int pl2 = tid >> 3;
    const int cg  = tid & 7;

    weight_prep(linear_w, lds_w, tid);
    __syncthreads();

    float g0[8], g1[8], g2[8], g3[8];
    #pragma unroll
    for (int k = 0; k < 8; ++k) {
        const float* wp = &lds_w[(cg + 8 * k) * 9];
        g0[k] = wp[0]; g1[k] = wp[1]; g2[k] = wp[2]; g3[k] = wp[3];
    }

    float s1a[8], s2a[8], mxv[8];
    #pragma unroll
    for (int k = 0; k < 8; ++k) { s1a[k] = 0.f; s2a[k] = 0.f; }

    process_chunk(features, num_voxels, coors, bid * PPB, tid,
                  lds_f, lds_pc, lds_w, g0, g1, g2, g3, s1a, s2a, mxv);

    {
        float* rp = rawmax + (size_t)(bid * PPB + pl2) * COUT + cg;
        #pragma unroll
        for (int k = 0; k < 8; ++k) rp[8 * k] = mxv[k];
    }

    #pragma unroll
    for (int k = 0; k < 8; ++k) {
        #pragma unroll
        for (int m = 8; m <= 32; m <<= 1) {
            s1a[k] += shfl_xor_f(s1a[k], m);
            s2a[k] += shfl_xor_f(s2a[k], m);
        }
    }
    {
        const int lane = tid & 63, wv = tid >> 6;
        if (lane < 8) {
            #pragma unroll
            for (int k = 0; k < 8; ++k) {
                lds_red[wv][lane][k]     = s1a[k];
                lds_red[wv][lane][8 + k] = s2a[k];
            }
        }
    }
    __syncthreads();
    {
        const int cg2 = tid >> 4, v = tid & 15;
        partials[bid * 128 + tid] = lds_red[0][cg2][v] + lds_red[1][cg2][v];
    }
}

__global__ __launch_bounds__(1024) void pfn_stats16(
    const float* __restrict__ partials, float* __restrict__ partials2)
{
    __shared__ double red[32][128];
    const int t = threadIdx.x, b = blockIdx.x;
    const int col4 = t & 31, j = t >> 5;
    const float4* p4 = (const float4*)partials;

    double a0 = 0.0, a1 = 0.0, a2 = 0.0, a3 = 0.0;
    #pragma unroll
    for (int i = 0; i < 5; ++i) {
        const int r = b + NSB_F * (j + 32 * i);
        if (r < NBLK_F) {
            const float4 v = p4[r * 32 + col4];
            a0 += (double)v.x; a1 += (double)v.y;
            a2 += (double)v.z; a3 += (double)v.w;
        }
    }
    red[j][col4 * 4 + 0] = a0;
    red[j][col4 * 4 + 1] = a1;
    red[j][col4 * 4 + 2] = a2;
    red[j][col4 * 4 + 3] = a3;
    __syncthreads();
    if (t < 128) {
        double s = 0.0;
        #pragma unroll
        for (int jj = 0; jj < 32; ++jj) s += red[jj][t];
        partials2[b * 128 + t] = (float)s;
    }
}

__global__ __launch_bounds__(256) void pfn_final(
    const float* __restrict__ partials2, const float* __restrict__ gamma,
    const float* __restrict__ beta, float* __restrict__ out)
{
    __shared__ double red[128];
    __shared__ float  sb[128];
    const int t = threadIdx.x;
    if (t < 128) {
        double s = 0.0;
        #pragma unroll
        for (int b = 0; b < NSB_F; ++b) s += (double)partials2[b * 128 + t];
        red[t] = s;
    }
    __syncthreads();
    if (t < 64) {
        const int cg = t & 7, k = t >> 3;
        const double s1 = red[cg * 16 + k];
        const double s2 = red[cg * 16 + 8 + k];
        const double PN = (double)PPIL * (double)NPTS;
        const double mean = s1 / PN;
        const double var  = s2 / PN - mean * mean;
        const double scale = (double)gamma[t] / sqrt(var + 1e-3);
        sb[t]      = (float)scale;
        sb[64 + t] = (float)((double)beta[t] - mean * scale);
    }
    __syncthreads();
    const int i  = blockIdx.x * 256 + t;
    const int u0 = (i & 15) * 4;
    float4 v = ((const float4*)out)[i];
    v.x = fmaxf(fmaf(v.x, sb[u0 + 0], sb[64 + u0 + 0]), 0.0f);
    v.y = fmaxf(fmaf(v.y, sb[u0 + 1], sb[64 + u0 + 1]), 0.0f);
    v.z = fmaxf(fmaf(v.z, sb[u0 + 2], sb[64 + u0 + 2]), 0.0f);
    v.w = fmaxf(fmaf(v.w, sb[u0 + 3], sb[64 + u0 + 3]), 0.0f);
    ((float4*)out)[i] = v;
}

// ---------------------------------------------------------------------------
extern "C" void kernel_launch(void* const* d_in, const int* in_sizes, int n_in,
                              void* d_out, int out_size, void* d_ws, size_t ws_size,
                              hipStream_t stream) {
    const float* features   = (const float*)d_in[0];
    const int*   num_voxels = (const int*)d_in[1];
    const int*   coors      = (const int*)d_in[2];
    const float* linear_w   = (const float*)d_in[3];
    const float* gamma      = (const float*)d_in[4];
    const float* beta       = (const float*)d_in[5];

    float* out = (float*)d_out;
    float* wsf = (float*)d_ws;
    // coop region
    float* partials  = wsf;                    // NBLK*128 = 160K floats
    float* partials2 = wsf + NBLK * 128;       // NSB*128
    // fallback region (disjoint)
    float* fpartials  = wsf + 262144;          // NBLK_F*128 = 320K floats
    float* fpartials2 = fpartials + NBLK_F * 128;

    void* args[] = {
        (void*)&features, (void*)&num_voxels, (void*)&coors, (void*)&linear_w,
        (void*)&gamma, (void*)&beta, (void*)&out, (void*)&partials, (void*)&partials2
    };
    hipError_t err = hipLaunchCooperativeKernel((void*)pfn_fused, dim3(NBLK),
                                                dim3(128), args, 0, stream);
    if (err != hipSuccess) {
        // fallback: proven 3-kernel path
        pfn_main<<<NBLK_F, 128, 0, stream>>>(features, num_voxels, coors,
                                             linear_w, out, fpartials);
        pfn_stats16<<<NSB_F, 1024, 0, stream>>>(fpartials, fpartials2);
        pfn_final<<<NBLK_F, 256, 0, stream>>>(fpartials2, gamma, beta, out);
    }
}

// Round 8
// 36.413 us; speedup vs baseline: 6.7844x; 6.7844x over previous
//
#include <hip/hip_runtime.h>
#include <float.h>
#include <math.h>

#define PPIL   40000
#define NPTS   32
#define COUT   64
#define PPB    16              // pillars per main block
#define NBLK_F 2500            // main blocks
#define PSTRIDE 132            // floats per pillar slot (33 float4: bank spread)
#define NSB_F  16              // stats reducer blocks

__device__ __forceinline__ float shfl_xor_f(float v, int m) {
    return __shfl_xor(v, m, 64);
}

// ===========================================================================
// Per-chunk worker: stage 16 pillars, pillar tree, affine phase 2.
// Accumulates s1/s2 into s1a/s2a, returns per-channel maxima in mxv[8].
// ===========================================================================
__device__ __forceinline__ void process_chunk(
    const float* __restrict__ features, const int* __restrict__ num_voxels,
    const int* __restrict__ coors, int pb, int tid,
    float* lds_f, float (*lds_pc)[12], const float* lds_w,
    const float g0[8], const float g1[8], const float g2[8], const float g3[8],
    float s1a[8], float s2a[8], float mxv[8])
{
    const int pl2 = tid >> 3;      // pillar in chunk, 0..15
    const int cg  = tid & 7;       // channel group

    // per-pillar scalars
    if (tid < PPB) {
        const int p = pb + tid;
        lds_pc[tid][3] = (float)coors[p * 4 + 3] * 0.2f + 0.1f;    // ax
        lds_pc[tid][4] = (float)coors[p * 4 + 2] * 0.2f - 39.9f;   // by
        lds_pc[tid][5] = (float)num_voxels[p];
    }

    // coalesced unmasked stage
    #pragma unroll
    for (int j = 0; j < 4; ++j) {
        const int idx = tid + 128 * j;        // 0..511
        const int pl  = idx >> 5, n = idx & 31;
        const float4 f = *(const float4*)(features + ((size_t)(pb + pl) * NPTS + n) * 4);
        *(float4*)&lds_f[pl * PSTRIDE + n * 4] = f;
    }
    __syncthreads();

    // pillar-sum tree: 8 threads per pillar, 4 points each
    {
        const int pl = tid >> 3, sub = tid & 7;
        const int nv = (int)lds_pc[pl][5];
        float sx = 0.f, sy = 0.f, sz = 0.f;
        float t0 = 0.f, t1 = 0.f, t2 = 0.f, t3 = 0.f;
        #pragma unroll
        for (int i = 0; i < 4; ++i) {
            const int n = sub + 8 * i;
            const float4 f = *(const float4*)&lds_f[pl * PSTRIDE + n * 4];
            sx += f.x; sy += f.y; sz += f.z;
            const float m = (n < nv) ? 1.0f : 0.0f;
            t0 = fmaf(f.x, m, t0); t1 = fmaf(f.y, m, t1);
            t2 = fmaf(f.z, m, t2); t3 = fmaf(f.w, m, t3);
        }
        #pragma unroll
        for (int m = 1; m <= 4; m <<= 1) {
            sx += shfl_xor_f(sx, m); sy += shfl_xor_f(sy, m); sz += shfl_xor_f(sz, m);
            t0 += shfl_xor_f(t0, m); t1 += shfl_xor_f(t1, m);
            t2 += shfl_xor_f(t2, m); t3 += shfl_xor_f(t3, m);
        }
        if (sub == 0) {
            const float inv = 1.0f / lds_pc[pl][5];
            lds_pc[pl][0] = sx * inv;
            lds_pc[pl][1] = sy * inv;
            lds_pc[pl][2] = sz * inv;
            lds_pc[pl][6] = t0; lds_pc[pl][7] = t1;
            lds_pc[pl][8] = t2; lds_pc[pl][9] = t3;
        }
    }
    __syncthreads();

    // phase 2
    const float* pc = lds_pc[pl2];
    const float mxp = pc[0], myp = pc[1], mzp = pc[2], axp = pc[3], byp = pc[4];
    const float nvf = pc[5];
    const float Fm0 = pc[6], Fm1 = pc[7], Fm2 = pc[8], Fm3 = pc[9];
    const int   nvi = (int)nvf;

    float cc[8];
    #pragma unroll
    for (int k = 0; k < 8; ++k) {
        const float* wp = &lds_w[(cg + 8 * k) * 9];
        cc[k] = -(wp[4] * mxp + wp[5] * myp + wp[6] * mzp + wp[7] * axp + wp[8] * byp);
    }

    float s2[8];
    #pragma unroll
    for (int k = 0; k < 8; ++k) { s2[k] = 0.0f; mxv[k] = -FLT_MAX; }

    const float4* fb = (const float4*)&lds_f[pl2 * PSTRIDE];
    #pragma unroll 2
    for (int n = 0; n < NPTS; ++n) {
        const float4 f = fb[n];
        const float mskf = (n < nvi) ? 1.0f : 0.0f;
        #pragma unroll
        for (int k = 0; k < 8; ++k) {
            float x = cc[k];
            x = fmaf(g0[k], f.x, x);
            x = fmaf(g1[k], f.y, x);
            x = fmaf(g2[k], f.z, x);
            x = fmaf(g3[k], f.w, x);
            x *= mskf;                        // exact 0 for masked rows
            s2[k]  = fmaf(x, x, s2[k]);
            mxv[k] = fmaxf(mxv[k], x);
        }
    }

    #pragma unroll
    for (int k = 0; k < 8; ++k) {
        float d = g0[k] * Fm0;
        d = fmaf(g1[k], Fm1, d);
        d = fmaf(g2[k], Fm2, d);
        d = fmaf(g3[k], Fm3, d);
        s1a[k] += fmaf(nvf, cc[k], d);
        s2a[k] += s2[k];
    }
}

__device__ __forceinline__ void weight_prep(const float* __restrict__ linear_w,
                                            float* lds_w, int tid)
{
    if (tid < 64) {
        const float* wr = linear_w + tid * 9;
        const float w0 = wr[0], w1 = wr[1], w2 = wr[2], w3 = wr[3], w4 = wr[4];
        const float w5 = wr[5], w6 = wr[6], w7 = wr[7], w8 = wr[8];
        float* dw = &lds_w[tid * 9];
        dw[0] = w0 + w4 + w7;
        dw[1] = w1 + w5 + w8;
        dw[2] = w2 + w6;
        dw[3] = w3;
        dw[4] = w4; dw[5] = w5; dw[6] = w6; dw[7] = w7; dw[8] = w8;
    }
}

// ===========================================================================
// Kernel A. __launch_bounds__(128, 6): VGPR cap ~85 (64 live per R7 build),
// 6 waves/EU -> 12 blocks/CU, matching the ~12.5KB-LDS cap. This is the
// occupancy/latency fix for the stall-dominated main kernel.
// ===========================================================================
__global__ __launch_bounds__(128, 6) void pfn_main(
    const float* __restrict__ features, const int* __restrict__ num_voxels,
    const int* __restrict__ coors, const float* __restrict__ linear_w,
    float* __restrict__ rawmax, float* __restrict__ partials)
{
    __shared__ float lds_f[PPB * PSTRIDE];
    __shared__ float lds_pc[PPB][12];
    __shared__ float lds_w[64 * 9];
    __shared__ float lds_red[2][8][16];

    const int tid = threadIdx.x;
    const int bid = blockIdx.x;
    const int pl2 = tid >> 3;
    const int cg  = tid & 7;

    weight_prep(linear_w, lds_w, tid);
    __syncthreads();

    float g0[8], g1[8], g2[8], g3[8];
    #pragma unroll
    for (int k = 0; k < 8; ++k) {
        const float* wp = &lds_w[(cg + 8 * k) * 9];
        g0[k] = wp[0]; g1[k] = wp[1]; g2[k] = wp[2]; g3[k] = wp[3];
    }

    float s1a[8], s2a[8], mxv[8];
    #pragma unroll
    for (int k = 0; k < 8; ++k) { s1a[k] = 0.f; s2a[k] = 0.f; }

    process_chunk(features, num_voxels, coors, bid * PPB, tid,
                  lds_f, lds_pc, lds_w, g0, g1, g2, g3, s1a, s2a, mxv);

    {
        float* rp = rawmax + (size_t)(bid * PPB + pl2) * COUT + cg;
        #pragma unroll
        for (int k = 0; k < 8; ++k) rp[8 * k] = mxv[k];
    }

    #pragma unroll
    for (int k = 0; k < 8; ++k) {
        #pragma unroll
        for (int m = 8; m <= 32; m <<= 1) {
            s1a[k] += shfl_xor_f(s1a[k], m);
            s2a[k] += shfl_xor_f(s2a[k], m);
        }
    }
    {
        const int lane = tid & 63, wv = tid >> 6;
        if (lane < 8) {
            #pragma unroll
            for (int k = 0; k < 8; ++k) {
                lds_red[wv][lane][k]     = s1a[k];
                lds_red[wv][lane][8 + k] = s2a[k];
            }
        }
    }
    __syncthreads();
    {
        const int cg2 = tid >> 4, v = tid & 15;
        partials[bid * 128 + tid] = lds_red[0][cg2][v] + lds_red[1][cg2][v];
    }
}

// ===========================================================================
// Kernel B: 16 blocks reduce partials rows (double, 4-deep ILP) -> partials2.
// ===========================================================================
__global__ __launch_bounds__(1024) void pfn_stats16(
    const float* __restrict__ partials, float* __restrict__ partials2)
{
    __shared__ double red[32][128];
    const int t = threadIdx.x, b = blockIdx.x;
    const int col4 = t & 31, j = t >> 5;
    const float4* p4 = (const float4*)partials;

    double a0 = 0.0, a1 = 0.0, a2 = 0.0, a3 = 0.0;
    #pragma unroll
    for (int i = 0; i < 5; ++i) {
        const int r = b + NSB_F * (j + 32 * i);
        if (r < NBLK_F) {
            const float4 v = p4[r * 32 + col4];
            a0 += (double)v.x; a1 += (double)v.y;
            a2 += (double)v.z; a3 += (double)v.w;
        }
    }
    red[j][col4 * 4 + 0] = a0;
    red[j][col4 * 4 + 1] = a1;
    red[j][col4 * 4 + 2] = a2;
    red[j][col4 * 4 + 3] = a3;
    __syncthreads();
    if (t < 128) {
        double s = 0.0;
        #pragma unroll
        for (int jj = 0; jj < 32; ++jj) s += red[jj][t];
        partials2[b * 128 + t] = (float)s;
    }
}

// ===========================================================================
// Kernel C: per-block combine of partials2 (8KB, L2-hot) -> scale/bias,
// then out = relu(rawmax*scale+bias) in place on d_out.
// ===========================================================================
__global__ __launch_bounds__(256) void pfn_final(
    const float* __restrict__ partials2, const float* __restrict__ gamma,
    const float* __restrict__ beta, float* __restrict__ out)
{
    __shared__ double red[128];
    __shared__ float  sb[128];
    const int t = threadIdx.x;
    if (t < 128) {
        double s = 0.0;
        #pragma unroll
        for (int b = 0; b < NSB_F; ++b) s += (double)partials2[b * 128 + t];
        red[t] = s;
    }
    __syncthreads();
    if (t < 64) {
        const int cg = t & 7, k = t >> 3;
        const double s1 = red[cg * 16 + k];
        const double s2 = red[cg * 16 + 8 + k];
        const double PN = (double)PPIL * (double)NPTS;
        const double mean = s1 / PN;
        const double var  = s2 / PN - mean * mean;
        const double scale = (double)gamma[t] / sqrt(var + 1e-3);
        sb[t]      = (float)scale;
        sb[64 + t] = (float)((double)beta[t] - mean * scale);
    }
    __syncthreads();
    const int i  = blockIdx.x * 256 + t;   // 640000 = 2500*256
    const int u0 = (i & 15) * 4;
    float4 v = ((const float4*)out)[i];
    v.x = fmaxf(fmaf(v.x, sb[u0 + 0], sb[64 + u0 + 0]), 0.0f);
    v.y = fmaxf(fmaf(v.y, sb[u0 + 1], sb[64 + u0 + 1]), 0.0f);
    v.z = fmaxf(fmaf(v.z, sb[u0 + 2], sb[64 + u0 + 2]), 0.0f);
    v.w = fmaxf(fmaf(v.w, sb[u0 + 3], sb[64 + u0 + 3]), 0.0f);
    ((float4*)out)[i] = v;
}

// ---------------------------------------------------------------------------
extern "C" void kernel_launch(void* const* d_in, const int* in_sizes, int n_in,
                              void* d_out, int out_size, void* d_ws, size_t ws_size,
                              hipStream_t stream) {
    const float* features   = (const float*)d_in[0];
    const int*   num_voxels = (const int*)d_in[1];
    const int*   coors      = (const int*)d_in[2];
    const float* linear_w   = (const float*)d_in[3];
    const float* gamma      = (const float*)d_in[4];
    const float* beta       = (const float*)d_in[5];

    float* out = (float*)d_out;
    float* wsf = (float*)d_ws;
    float* partials  = wsf;                    // NBLK_F*128 = 320K floats
    float* partials2 = wsf + NBLK_F * 128;     // NSB_F*128 floats

    pfn_main<<<NBLK_F, 128, 0, stream>>>(features, num_voxels, coors,
                                         linear_w, out, partials);
    pfn_stats16<<<NSB_F, 1024, 0, stream>>>(partials, partials2);
    pfn_final<<<NBLK_F, 256, 0, stream>>>(partials2, gamma, beta, out);
}

// Round 9
// 32.156 us; speedup vs baseline: 7.6825x; 1.1324x over previous
//
#include <hip/hip_runtime.h>
#include <float.h>
#include <math.h>

#define PPIL   40000
#define NPTS   32
#define COUT   64
#define PPB    16              // pillars per main block
#define NBLK_F 2500            // main blocks
#define PSTRIDE 132            // floats per pillar slot (33 float4: bank spread)
#define NSB_F  16              // stats reducer blocks

__device__ __forceinline__ float shfl_xor_f(float v, int m) {
    return __shfl_xor(v, m, 64);
}

// ===========================================================================
// Per-chunk worker: stage 16 pillars, pillar tree, affine phase 2.
// Phase 2 iterates n < nv only: masked rows contribute 0 to s2, and the max
// is clamped with 0 afterwards (exact masked semantics). s1 is factored.
// ===========================================================================
__device__ __forceinline__ void process_chunk(
    const float* __restrict__ features, const int* __restrict__ num_voxels,
    const int* __restrict__ coors, int pb, int tid,
    float* lds_f, float (*lds_pc)[12], const float* lds_w,
    const float g0[8], const float g1[8], const float g2[8], const float g3[8],
    float s1a[8], float s2a[8], float mxv[8])
{
    const int pl2 = tid >> 3;      // pillar in chunk, 0..15
    const int cg  = tid & 7;       // channel group

    // per-pillar scalars
    if (tid < PPB) {
        const int p = pb + tid;
        lds_pc[tid][3] = (float)coors[p * 4 + 3] * 0.2f + 0.1f;    // ax
        lds_pc[tid][4] = (float)coors[p * 4 + 2] * 0.2f - 39.9f;   // by
        lds_pc[tid][5] = (float)num_voxels[p];
    }

    // coalesced unmasked stage
    #pragma unroll
    for (int j = 0; j < 4; ++j) {
        const int idx = tid + 128 * j;        // 0..511
        const int pl  = idx >> 5, n = idx & 31;
        const float4 f = *(const float4*)(features + ((size_t)(pb + pl) * NPTS + n) * 4);
        *(float4*)&lds_f[pl * PSTRIDE + n * 4] = f;
    }
    __syncthreads();

    // pillar-sum tree: 8 threads per pillar, 4 points each
    {
        const int pl = tid >> 3, sub = tid & 7;
        const int nv = (int)lds_pc[pl][5];
        float sx = 0.f, sy = 0.f, sz = 0.f;
        float t0 = 0.f, t1 = 0.f, t2 = 0.f, t3 = 0.f;
        #pragma unroll
        for (int i = 0; i < 4; ++i) {
            const int n = sub + 8 * i;
            const float4 f = *(const float4*)&lds_f[pl * PSTRIDE + n * 4];
            sx += f.x; sy += f.y; sz += f.z;
            const float m = (n < nv) ? 1.0f : 0.0f;
            t0 = fmaf(f.x, m, t0); t1 = fmaf(f.y, m, t1);
            t2 = fmaf(f.z, m, t2); t3 = fmaf(f.w, m, t3);
        }
        #pragma unroll
        for (int m = 1; m <= 4; m <<= 1) {
            sx += shfl_xor_f(sx, m); sy += shfl_xor_f(sy, m); sz += shfl_xor_f(sz, m);
            t0 += shfl_xor_f(t0, m); t1 += shfl_xor_f(t1, m);
            t2 += shfl_xor_f(t2, m); t3 += shfl_xor_f(t3, m);
        }
        if (sub == 0) {
            const float inv = 1.0f / lds_pc[pl][5];
            lds_pc[pl][0] = sx * inv;
            lds_pc[pl][1] = sy * inv;
            lds_pc[pl][2] = sz * inv;
            lds_pc[pl][6] = t0; lds_pc[pl][7] = t1;
            lds_pc[pl][8] = t2; lds_pc[pl][9] = t3;
        }
    }
    __syncthreads();

    // phase 2
    const float* pc = lds_pc[pl2];
    const float mxp = pc[0], myp = pc[1], mzp = pc[2], axp = pc[3], byp = pc[4];
    const float nvf = pc[5];
    const float Fm0 = pc[6], Fm1 = pc[7], Fm2 = pc[8], Fm3 = pc[9];
    const int   nvi = (int)nvf;

    float cc[8];
    #pragma unroll
    for (int k = 0; k < 8; ++k) {
        const float* wp = &lds_w[(cg + 8 * k) * 9];
        cc[k] = -(wp[4] * mxp + wp[5] * myp + wp[6] * mzp + wp[7] * axp + wp[8] * byp);
    }

    float s2[8];
    #pragma unroll
    for (int k = 0; k < 8; ++k) { s2[k] = 0.0f; mxv[k] = -FLT_MAX; }

    const float4* fb = (const float4*)&lds_f[pl2 * PSTRIDE];
    for (int n = 0; n < nvi; ++n) {          // valid rows only (nv >= 1 always)
        const float4 f = fb[n];
        #pragma unroll
        for (int k = 0; k < 8; ++k) {
            float x = cc[k];
            x = fmaf(g0[k], f.x, x);
            x = fmaf(g1[k], f.y, x);
            x = fmaf(g2[k], f.z, x);
            x = fmaf(g3[k], f.w, x);
            s2[k]  = fmaf(x, x, s2[k]);
            mxv[k] = fmaxf(mxv[k], x);
        }
    }
    if (nvi < NPTS) {                        // masked rows are exact zeros
        #pragma unroll
        for (int k = 0; k < 8; ++k) mxv[k] = fmaxf(mxv[k], 0.0f);
    }

    #pragma unroll
    for (int k = 0; k < 8; ++k) {
        float d = g0[k] * Fm0;
        d = fmaf(g1[k], Fm1, d);
        d = fmaf(g2[k], Fm2, d);
        d = fmaf(g3[k], Fm3, d);
        s1a[k] += fmaf(nvf, cc[k], d);
        s2a[k] += s2[k];
    }
}

__device__ __forceinline__ void weight_prep(const float* __restrict__ linear_w,
                                            float* lds_w, int tid)
{
    if (tid < 64) {
        const float* wr = linear_w + tid * 9;
        const float w0 = wr[0], w1 = wr[1], w2 = wr[2], w3 = wr[3], w4 = wr[4];
        const float w5 = wr[5], w6 = wr[6], w7 = wr[7], w8 = wr[8];
        float* dw = &lds_w[tid * 9];
        dw[0] = w0 + w4 + w7;
        dw[1] = w1 + w5 + w8;
        dw[2] = w2 + w6;
        dw[3] = w3;
        dw[4] = w4; dw[5] = w5; dw[6] = w6; dw[7] = w7; dw[8] = w8;
    }
}

// ===========================================================================
// Kernel A (R5-proven config: plain __launch_bounds__(128), no min-waves).
// ===========================================================================
__global__ __launch_bounds__(128) void pfn_main(
    const float* __restrict__ features, const int* __restrict__ num_voxels,
    const int* __restrict__ coors, const float* __restrict__ linear_w,
    float* __restrict__ rawmax, float* __restrict__ partials)
{
    __shared__ float lds_f[PPB * PSTRIDE];
    __shared__ float lds_pc[PPB][12];
    __shared__ float lds_w[64 * 9];
    __shared__ float lds_red[2][8][16];

    const int tid = threadIdx.x;
    const int bid = blockIdx.x;
    const int pl2 = tid >> 3;
    const int cg  = tid & 7;

    weight_prep(linear_w, lds_w, tid);
    __syncthreads();

    float g0[8], g1[8], g2[8], g3[8];
    #pragma unroll
    for (int k = 0; k < 8; ++k) {
        const float* wp = &lds_w[(cg + 8 * k) * 9];
        g0[k] = wp[0]; g1[k] = wp[1]; g2[k] = wp[2]; g3[k] = wp[3];
    }

    float s1a[8], s2a[8], mxv[8];
    #pragma unroll
    for (int k = 0; k < 8; ++k) { s1a[k] = 0.f; s2a[k] = 0.f; }

    process_chunk(features, num_voxels, coors, bid * PPB, tid,
                  lds_f, lds_pc, lds_w, g0, g1, g2, g3, s1a, s2a, mxv);

    {
        float* rp = rawmax + (size_t)(bid * PPB + pl2) * COUT + cg;
        #pragma unroll
        for (int k = 0; k < 8; ++k) rp[8 * k] = mxv[k];
    }

    #pragma unroll
    for (int k = 0; k < 8; ++k) {
        #pragma unroll
        for (int m = 8; m <= 32; m <<= 1) {
            s1a[k] += shfl_xor_f(s1a[k], m);
            s2a[k] += shfl_xor_f(s2a[k], m);
        }
    }
    {
        const int lane = tid & 63, wv = tid >> 6;
        if (lane < 8) {
            #pragma unroll
            for (int k = 0; k < 8; ++k) {
                lds_red[wv][lane][k]     = s1a[k];
                lds_red[wv][lane][8 + k] = s2a[k];
            }
        }
    }
    __syncthreads();
    {
        const int cg2 = tid >> 4, v = tid & 15;
        partials[bid * 128 + tid] = lds_red[0][cg2][v] + lds_red[1][cg2][v];
    }
}

// ===========================================================================
// Kernel B: 16 blocks reduce partials rows (double, float4 ILP) -> partials2.
// ===========================================================================
__global__ __launch_bounds__(1024) void pfn_stats16(
    const float* __restrict__ partials, float* __restrict__ partials2)
{
    __shared__ double red[32][128];
    const int t = threadIdx.x, b = blockIdx.x;
    const int col4 = t & 31, j = t >> 5;
    const float4* p4 = (const float4*)partials;

    double a0 = 0.0, a1 = 0.0, a2 = 0.0, a3 = 0.0;
    #pragma unroll
    for (int i = 0; i < 5; ++i) {
        const int r = b + NSB_F * (j + 32 * i);
        if (r < NBLK_F) {
            const float4 v = p4[r * 32 + col4];
            a0 += (double)v.x; a1 += (double)v.y;
            a2 += (double)v.z; a3 += (double)v.w;
        }
    }
    red[j][col4 * 4 + 0] = a0;
    red[j][col4 * 4 + 1] = a1;
    red[j][col4 * 4 + 2] = a2;
    red[j][col4 * 4 + 3] = a3;
    __syncthreads();
    if (t < 128) {
        double s = 0.0;
        #pragma unroll
        for (int jj = 0; jj < 32; ++jj) s += red[jj][t];
        partials2[b * 128 + t] = (float)s;
    }
}

// ===========================================================================
// Kernel C: per-block combine of partials2 (8KB, L2-hot); fp32 finalize
// (no double divides/sqrt -- ~1e-6 rel vs 0.57 threshold), then
// out = relu(rawmax*scale+bias) in place on d_out.
// ===========================================================================
__global__ __launch_bounds__(256) void pfn_final(
    const float* __restrict__ partials2, const float* __restrict__ gamma,
    const float* __restrict__ beta, float* __restrict__ out)
{
    __shared__ double red[128];
    __shared__ float  sb[128];
    const int t = threadIdx.x;
    if (t < 128) {
        double s = 0.0;
        #pragma unroll
        for (int b = 0; b < NSB_F; ++b) s += (double)partials2[b * 128 + t];
        red[t] = s;
    }
    __syncthreads();
    if (t < 64) {
        const int cg = t & 7, k = t >> 3;
        const float s1 = (float)red[cg * 16 + k];
        const float s2 = (float)red[cg * 16 + 8 + k];
        const float invPN = 1.0f / ((float)PPIL * (float)NPTS);
        const float mean  = s1 * invPN;
        const float var   = fmaf(-mean, mean, s2 * invPN);
        const float scale = gamma[t] * rsqrtf(var + 1e-3f);
        sb[t]      = scale;
        sb[64 + t] = fmaf(-mean, scale, beta[t]);
    }
    __syncthreads();
    const int i  = blockIdx.x * 256 + t;   // 640000 = 2500*256
    const int u0 = (i & 15) * 4;
    float4 v = ((const float4*)out)[i];
    v.x = fmaxf(fmaf(v.x, sb[u0 + 0], sb[64 + u0 + 0]), 0.0f);
    v.y = fmaxf(fmaf(v.y, sb[u0 + 1], sb[64 + u0 + 1]), 0.0f);
    v.z = fmaxf(fmaf(v.z, sb[u0 + 2], sb[64 + u0 + 2]), 0.0f);
    v.w = fmaxf(fmaf(v.w, sb[u0 + 3], sb[64 + u0 + 3]), 0.0f);
    ((float4*)out)[i] = v;
}

// ---------------------------------------------------------------------------
extern "C" void kernel_launch(void* const* d_in, const int* in_sizes, int n_in,
                              void* d_out, int out_size, void* d_ws, size_t ws_size,
                              hipStream_t stream) {
    const float* features   = (const float*)d_in[0];
    const int*   num_voxels = (const int*)d_in[1];
    const int*   coors      = (const int*)d_in[2];
    const float* linear_w   = (const float*)d_in[3];
    const float* gamma      = (const float*)d_in[4];
    const float* beta       = (const float*)d_in[5];

    float* out = (float*)d_out;
    float* wsf = (float*)d_ws;
    float* partials  = wsf;                    // NBLK_F*128 = 320K floats
    float* partials2 = wsf + NBLK_F * 128;     // NSB_F*128 floats

    pfn_main<<<NBLK_F, 128, 0, stream>>>(features, num_voxels, coors,
                                         linear_w, out, partials);
    pfn_stats16<<<NSB_F, 1024, 0, stream>>>(partials, partials2);
    pfn_final<<<NBLK_F, 256, 0, stream>>>(partials2, gamma, beta, out);
}

// Round 10
// 30.528 us; speedup vs baseline: 8.0921x; 1.0533x over previous
//
#include <hip/hip_runtime.h>
#include <hip/hip_fp16.h>
#include <float.h>
#include <math.h>

#define PPIL   40000
#define NPTS   32
#define COUT   64
#define PPB    16              // pillars per main block
#define NBLK_F 2500            // main blocks
#define PSTRIDE 132            // floats per pillar slot (33 float4: bank spread)
#define NSB_F  16              // stats reducer blocks
#define NFB    625             // final blocks (x1024 threads = 640000 float4)

__device__ __forceinline__ float shfl_xor_f(float v, int m) {
    return __shfl_xor(v, m, 64);
}

__device__ __forceinline__ void weight_prep(const float* __restrict__ linear_w,
                                            float* lds_w, int tid)
{
    if (tid < 64) {
        const float* wr = linear_w + tid * 9;
        const float w0 = wr[0], w1 = wr[1], w2 = wr[2], w3 = wr[3], w4 = wr[4];
        const float w5 = wr[5], w6 = wr[6], w7 = wr[7], w8 = wr[8];
        float* dw = &lds_w[tid * 9];
        dw[0] = w0 + w4 + w7;
        dw[1] = w1 + w5 + w8;
        dw[2] = w2 + w6;
        dw[3] = w3;
        dw[4] = w4; dw[5] = w5; dw[6] = w6; dw[7] = w7; dw[8] = w8;
    }
}

// ===========================================================================
// Kernel A. Thread (pl2 = tid>>3, cg = tid&7) owns pillar pl2 / channels
// u = cg*8..cg*8+7. Stage-to-LDS fused with register pillar sums + 3-round
// butterfly (masks 1,2,4) -> all pillar constants in registers. Phase 2:
// x = g.f + c over valid rows only. s1 factored. Block s1/s2 reduce via
// LDS [16][128] matrix overlaid on lds_f (no shuffles). rawmax -> fp16 ws.
// ===========================================================================
__global__ __launch_bounds__(128) void pfn_main(
    const float* __restrict__ features, const int* __restrict__ num_voxels,
    const int* __restrict__ coors, const float* __restrict__ linear_w,
    __half* __restrict__ rawh, float* __restrict__ partials)
{
    __shared__ float lds_f[PPB * PSTRIDE];   // staging; reused as [16][128] sums
    __shared__ float lds_w[64 * 9];

    const int tid = threadIdx.x;
    const int bid = blockIdx.x;
    const int pl2 = tid >> 3;     // pillar in chunk
    const int cg  = tid & 7;      // sub-index / channel group
    const int p   = bid * PPB + pl2;

    weight_prep(linear_w, lds_w, tid);

    // per-thread pillar scalars (8 threads/pillar read same dwords: cheap)
    const int   nvi = num_voxels[p];
    const float nvf = (float)nvi;
    const float axp = (float)coors[p * 4 + 3] * 0.2f + 0.1f;
    const float byp = (float)coors[p * 4 + 2] * 0.2f - 39.9f;

    // stage 4 owned points (n = cg + 8i) + register sums
    float sx = 0.f, sy = 0.f, sz = 0.f;
    float t0 = 0.f, t1 = 0.f, t2 = 0.f, t3 = 0.f;
    #pragma unroll
    for (int i = 0; i < 4; ++i) {
        const int n = cg + 8 * i;
        const float4 f = *(const float4*)(features + ((size_t)p * NPTS + n) * 4);
        *(float4*)&lds_f[pl2 * PSTRIDE + n * 4] = f;
        sx += f.x; sy += f.y; sz += f.z;
        const float m = (n < nvi) ? 1.0f : 0.0f;
        t0 = fmaf(f.x, m, t0); t1 = fmaf(f.y, m, t1);
        t2 = fmaf(f.z, m, t2); t3 = fmaf(f.w, m, t3);
    }
    #pragma unroll
    for (int m = 1; m <= 4; m <<= 1) {
        sx += shfl_xor_f(sx, m); sy += shfl_xor_f(sy, m); sz += shfl_xor_f(sz, m);
        t0 += shfl_xor_f(t0, m); t1 += shfl_xor_f(t1, m);
        t2 += shfl_xor_f(t2, m); t3 += shfl_xor_f(t3, m);
    }
    const float inv = 1.0f / nvf;
    const float mxp = sx * inv, myp = sy * inv, mzp = sz * inv;

    __syncthreads();    // lds_w ready + all staging writes visible

    float g0[8], g1[8], g2[8], g3[8], cc[8];
    #pragma unroll
    for (int k = 0; k < 8; ++k) {
        const float* wp = &lds_w[(cg * 8 + k) * 9];     // u = cg*8 + k
        g0[k] = wp[0]; g1[k] = wp[1]; g2[k] = wp[2]; g3[k] = wp[3];
        cc[k] = -(wp[4] * mxp + wp[5] * myp + wp[6] * mzp + wp[7] * axp + wp[8] * byp);
    }

    float s2v[8], mxv[8];
    #pragma unroll
    for (int k = 0; k < 8; ++k) { s2v[k] = 0.0f; mxv[k] = -FLT_MAX; }

    const float4* fb = (const float4*)&lds_f[pl2 * PSTRIDE];
    for (int n = 0; n < nvi; ++n) {          // valid rows only (nv >= 1)
        const float4 f = fb[n];
        #pragma unroll
        for (int k = 0; k < 8; ++k) {
            float x = fmaf(g0[k], f.x, cc[k]);
            x = fmaf(g1[k], f.y, x);
            x = fmaf(g2[k], f.z, x);
            x = fmaf(g3[k], f.w, x);
            s2v[k] = fmaf(x, x, s2v[k]);
            mxv[k] = fmaxf(mxv[k], x);
        }
    }
    if (nvi < NPTS) {                        // masked rows are exact zeros
        #pragma unroll
        for (int k = 0; k < 8; ++k) mxv[k] = fmaxf(mxv[k], 0.0f);
    }

    // factored s1: s1[u] = g_u . Fm + nv*c_u
    float s1v[8];
    #pragma unroll
    for (int k = 0; k < 8; ++k) {
        float d = g0[k] * t0;
        d = fmaf(g1[k], t1, d);
        d = fmaf(g2[k], t2, d);
        d = fmaf(g3[k], t3, d);
        s1v[k] = fmaf(nvf, cc[k], d);
    }

    // rawmax -> fp16, one 16B store per thread (contiguous u = cg*8..+7)
    {
        __half2 h0 = __floats2half2_rn(mxv[0], mxv[1]);
        __half2 h1 = __floats2half2_rn(mxv[2], mxv[3]);
        __half2 h2 = __floats2half2_rn(mxv[4], mxv[5]);
        __half2 h3 = __floats2half2_rn(mxv[6], mxv[7]);
        uint4 pk;
        pk.x = *(const unsigned int*)&h0;
        pk.y = *(const unsigned int*)&h1;
        pk.z = *(const unsigned int*)&h2;
        pk.w = *(const unsigned int*)&h3;
        *(uint4*)(rawh + (size_t)p * COUT + cg * 8) = pk;
    }

    // block reduce via LDS matrix [16][128] overlaid on lds_f
    __syncthreads();                         // phase-2 reads of lds_f done
    float* lsum = lds_f;
    *(float4*)&lsum[pl2 * 128 + cg * 8 + 0]      = make_float4(s1v[0], s1v[1], s1v[2], s1v[3]);
    *(float4*)&lsum[pl2 * 128 + cg * 8 + 4]      = make_float4(s1v[4], s1v[5], s1v[6], s1v[7]);
    *(float4*)&lsum[pl2 * 128 + 64 + cg * 8 + 0] = make_float4(s2v[0], s2v[1], s2v[2], s2v[3]);
    *(float4*)&lsum[pl2 * 128 + 64 + cg * 8 + 4] = make_float4(s2v[4], s2v[5], s2v[6], s2v[7]);
    __syncthreads();

    // column sum: partials[bid][t]  (t<64: s1[u=t], t>=64: s2[u=t-64])
    float acc = 0.0f;
    #pragma unroll
    for (int r = 0; r < 16; ++r) acc += lsum[r * 128 + tid];
    partials[bid * 128 + tid] = acc;
}

// ===========================================================================
// Kernel B: 16 blocks reduce partials rows (double, float4 ILP) -> partials2.
// Column-layout agnostic.
// ===========================================================================
__global__ __launch_bounds__(1024) void pfn_stats16(
    const float* __restrict__ partials, float* __restrict__ partials2)
{
    __shared__ double red[32][128];
    const int t = threadIdx.x, b = blockIdx.x;
    const int col4 = t & 31, j = t >> 5;
    const float4* p4 = (const float4*)partials;

    double a0 = 0.0, a1 = 0.0, a2 = 0.0, a3 = 0.0;
    #pragma unroll
    for (int i = 0; i < 5; ++i) {
        const int r = b + NSB_F * (j + 32 * i);
        if (r < NBLK_F) {
            const float4 v = p4[r * 32 + col4];
            a0 += (double)v.x; a1 += (double)v.y;
            a2 += (double)v.z; a3 += (double)v.w;
        }
    }
    red[j][col4 * 4 + 0] = a0;
    red[j][col4 * 4 + 1] = a1;
    red[j][col4 * 4 + 2] = a2;
    red[j][col4 * 4 + 3] = a3;
    __syncthreads();
    if (t < 128) {
        double s = 0.0;
        #pragma unroll
        for (int jj = 0; jj < 32; ++jj) s += red[jj][t];
        partials2[b * 128 + t] = (float)s;
    }
}

// ===========================================================================
// Kernel C: 625 blocks x 1024 threads. Combine partials2 (8KB, L2-hot),
// fp32 finalize, then out = relu(rawh_fp16 * scale + bias) (coalesced).
// ===========================================================================
__global__ __launch_bounds__(1024) void pfn_final(
    const float* __restrict__ partials2, const float* __restrict__ gamma,
    const float* __restrict__ beta, const __half* __restrict__ rawh,
    float* __restrict__ out)
{
    __shared__ double red[128];
    __shared__ float  sb[128];
    const int t = threadIdx.x;
    if (t < 128) {
        double s = 0.0;
        #pragma unroll
        for (int b = 0; b < NSB_F; ++b) s += (double)partials2[b * 128 + t];
        red[t] = s;
    }
    __syncthreads();
    if (t < 64) {
        const float s1 = (float)red[t];
        const float s2 = (float)red[64 + t];
        const float invPN = 1.0f / ((float)PPIL * (float)NPTS);
        const float mean  = s1 * invPN;
        const float var   = fmaf(-mean, mean, s2 * invPN);
        const float scale = gamma[t] * rsqrtf(var + 1e-3f);
        sb[t]      = scale;
        sb[64 + t] = fmaf(-mean, scale, beta[t]);
    }
    __syncthreads();

    const int i  = blockIdx.x * 1024 + t;    // 640000 = 625*1024
    const int u0 = (i & 15) * 4;             // 4 consecutive channels
    const uint2 pk = *(const uint2*)(rawh + (size_t)i * 4);
    const __half2 h01 = *(const __half2*)&pk.x;
    const __half2 h23 = *(const __half2*)&pk.y;
    float4 v;
    v.x = fmaxf(fmaf(__low2float(h01),  sb[u0 + 0], sb[64 + u0 + 0]), 0.0f);
    v.y = fmaxf(fmaf(__high2float(h01), sb[u0 + 1], sb[64 + u0 + 1]), 0.0f);
    v.z = fmaxf(fmaf(__low2float(h23),  sb[u0 + 2], sb[64 + u0 + 2]), 0.0f);
    v.w = fmaxf(fmaf(__high2float(h23), sb[u0 + 3], sb[64 + u0 + 3]), 0.0f);
    ((float4*)out)[i] = v;
}

// ---------------------------------------------------------------------------
extern "C" void kernel_launch(void* const* d_in, const int* in_sizes, int n_in,
                              void* d_out, int out_size, void* d_ws, size_t ws_size,
                              hipStream_t stream) {
    const float* features   = (const float*)d_in[0];
    const int*   num_voxels = (const int*)d_in[1];
    const int*   coors      = (const int*)d_in[2];
    const float* linear_w   = (const float*)d_in[3];
    const float* gamma      = (const float*)d_in[4];
    const float* beta       = (const float*)d_in[5];

    float*  out       = (float*)d_out;
    float*  wsf       = (float*)d_ws;
    float*  partials  = wsf;                    // NBLK_F*128 = 320K floats
    float*  partials2 = wsf + NBLK_F * 128;     // NSB_F*128 floats
    __half* rawh      = (__half*)(wsf + (1 << 20));  // 5.12 MB at +4MB offset

    pfn_main<<<NBLK_F, 128, 0, stream>>>(features, num_voxels, coors,
                                         linear_w, rawh, partials);
    pfn_stats16<<<NSB_F, 1024, 0, stream>>>(partials, partials2);
    pfn_final<<<NFB, 1024, 0, stream>>>(partials2, gamma, beta, rawh, out);
}